// Round 2
// baseline (402.368 us; speedup 1.0000x reference)
//
#include <hip/hip_runtime.h>
#include <math.h>

#define DIMC 256
#define NH 8
#define NPIX 16384          // 128*128
#define BATCH 16
#define ATT_SCALE 0.17677669529663687f   // 1/sqrt(32)
#define LN_EPS 1e-5f

#define NT 64               // n per LDS tile
#define TPB 8               // tiles per block
#define BPB 32              // blocks per batch = NPIX/(NT*TPB)
#define NSLAB 32            // s_part slabs per batch (= BPB)

// ---------------------------------------------------------------------------
// K0: qk[b][h][c] = SCALE * sum_d q[b][h*32+d] * Wkv[h*32+d][c]
//     with q[b][i] = sum_c audio[b][c] * Wq[i][c]
// ---------------------------------------------------------------------------
__global__ __launch_bounds__(256) void k_qk(const float* __restrict__ audio,
                                            const float* __restrict__ Wq,
                                            const float* __restrict__ Wkv,
                                            float* __restrict__ qk) {
    int b = blockIdx.x;
    int t = threadIdx.x;
    __shared__ float aud[DIMC];
    __shared__ float qL[DIMC];
    aud[t] = audio[b * DIMC + t];
    __syncthreads();
    {
        const float* wr = Wq + (size_t)t * DIMC;
        float acc = 0.f;
        for (int c = 0; c < DIMC; c += 4) {
            float4 w = *(const float4*)(wr + c);
            acc = fmaf(w.x, aud[c], acc);
            acc = fmaf(w.y, aud[c + 1], acc);
            acc = fmaf(w.z, aud[c + 2], acc);
            acc = fmaf(w.w, aud[c + 3], acc);
        }
        qL[t] = acc;
    }
    __syncthreads();
    {
        int c = t;
        float acc = 0.f;
        for (int i = 0; i < DIMC; ++i) {
            acc = fmaf(qL[i], Wkv[(size_t)i * DIMC + c], acc);
            if ((i & 31) == 31) {
                qk[((size_t)b * NH + (i >> 5)) * DIMC + c] = ATT_SCALE * acc;
                acc = 0.f;
            }
        }
    }
}

// ---------------------------------------------------------------------------
// K1 (fused attn + s): one fm read for both reductions.
// grid = BATCH*BPB = 512 blocks (2 blocks/CU, one round), 256 threads.
// LDS tile fmT[c][n'] xor-swizzled: word = c*64 + (n ^ ((c&7)<<2)).
//   - load:    lanes walk n-groups within rows  -> b128 writes, conflict-free
//   - phase A: lanes = n, walk c (column read)  -> b32, xor makes it conflict-free
//   - phase B: lanes = c, walk n (row read)     -> b128, xor spans spread banks
// ---------------------------------------------------------------------------
__global__ __launch_bounds__(256) void k_fused(const float* __restrict__ fm,
                                               const float* __restrict__ qk,
                                               float* __restrict__ s_part) {
    __shared__ float fmT[DIMC * NT];      // 64 KB
    __shared__ float qkL[DIMC * NH];      // 8 KB, [c][h]
    __shared__ float pA[4 * NH * NT];     // 8 KB, [cg][h][n]; pA[0..511] reused as aS[h][n]

    int blk = blockIdx.x;
    int b = blk >> 5;
    int j = blk & 31;
    int t = threadIdx.x;

    // qk -> qkL[c*8+h]   (coalesced global read, one-time transpose write)
    for (int k = 0; k < NH; ++k)
        qkL[t * NH + k] = qk[((size_t)b * NH + k) * DIMC + t];

    float sc[NH];
#pragma unroll
    for (int h = 0; h < NH; ++h) sc[h] = 0.f;
    __syncthreads();

    const int n_l = t & 63;
    const int cg  = t >> 6;

    for (int tile = 0; tile < TPB; ++tile) {
        const int n0 = j * (NT * TPB) + tile * NT;

        // ---- global -> LDS (64 KB, coalesced 1KB/wave-instr) ----
#pragma unroll
        for (int k = 0; k < 16; ++k) {
            int flat = k * 256 + t;
            int c = flat >> 4, g = flat & 15;
            float4 v = *(const float4*)(fm + ((size_t)b * DIMC + c) * NPIX + n0 + g * 4);
            *(float4*)(fmT + c * NT + ((g * 4) ^ ((c & 7) << 2))) = v;
        }
        __syncthreads();

        // ---- phase A: partial attn over this thread's 64-c range ----
        float att0x = 0.f, att0y = 0.f, att0z = 0.f, att0w = 0.f;
        float att1x = 0.f, att1y = 0.f, att1z = 0.f, att1w = 0.f;
#pragma unroll 8
        for (int cc = 0; cc < 64; ++cc) {
            int c = cg * 64 + cc;
            float v = fmT[c * NT + (n_l ^ ((c & 7) << 2))];
            float4 q0 = *(const float4*)(qkL + c * NH);
            float4 q1 = *(const float4*)(qkL + c * NH + 4);
            att0x = fmaf(v, q0.x, att0x);
            att0y = fmaf(v, q0.y, att0y);
            att0z = fmaf(v, q0.z, att0z);
            att0w = fmaf(v, q0.w, att0w);
            att1x = fmaf(v, q1.x, att1x);
            att1y = fmaf(v, q1.y, att1y);
            att1z = fmaf(v, q1.z, att1z);
            att1w = fmaf(v, q1.w, att1w);
        }
        {
            float* p = pA + cg * (NH * NT) + n_l;
            p[0 * NT] = att0x; p[1 * NT] = att0y; p[2 * NT] = att0z; p[3 * NT] = att0w;
            p[4 * NT] = att1x; p[5 * NT] = att1y; p[6 * NT] = att1z; p[7 * NT] = att1w;
        }
        __syncthreads();

        // ---- reduce 4 partials + spike -> aS[h][n] (aliased onto pA[0]) ----
#pragma unroll
        for (int k = 0; k < 2; ++k) {
            int idx = k * 256 + t;           // (h = idx>>6 in 0..7, n = idx&63)
            int h = idx >> 6, n = idx & 63;
            float sum = pA[(0 * NH + h) * NT + n] + pA[(1 * NH + h) * NT + n]
                      + pA[(2 * NH + h) * NT + n] + pA[(3 * NH + h) * NT + n];
            pA[h * NT + n] = rintf(fminf(fmaxf(sum, 0.f), 4.f)) * 0.25f;
        }
        __syncthreads();

        // ---- phase B: sc[h] += sum_n fm[c][n] * aS[h][n], c = t ----
        {
            const int c = t;
            const int xorc = (c & 7) << 2;
            float4 fr[16];
#pragma unroll
            for (int g = 0; g < 16; ++g)
                fr[g] = *(const float4*)(fmT + c * NT + ((g * 4) ^ xorc));
#pragma unroll
            for (int h = 0; h < NH; ++h) {
                float acc = 0.f;
#pragma unroll
                for (int g = 0; g < 16; ++g) {
                    float4 av = *(const float4*)(pA + h * NT + g * 4);
                    acc = fmaf(fr[g].x, av.x, acc);
                    acc = fmaf(fr[g].y, av.y, acc);
                    acc = fmaf(fr[g].z, av.z, acc);
                    acc = fmaf(fr[g].w, av.w, acc);
                }
                sc[h] += acc;
            }
        }
        __syncthreads();   // protect fmT/pA before next tile overwrites
    }

    // s_part[b][j][h][c]
#pragma unroll
    for (int h = 0; h < NH; ++h)
        s_part[(((size_t)b * NSLAB + j) * NH + h) * DIMC + t] = sc[h];
}

// ---------------------------------------------------------------------------
// K2: s[b][h][c] = sum_slab s_part  (128 blocks, coalesced)
// ---------------------------------------------------------------------------
__global__ __launch_bounds__(256) void k_red(const float* __restrict__ s_part,
                                             float* __restrict__ s) {
    int bh = blockIdx.x;                 // b*8 + h
    int b = bh >> 3, h = bh & 7;
    int c = threadIdx.x;
    float acc = 0.f;
    for (int sl = 0; sl < NSLAB; ++sl)
        acc += s_part[(((size_t)b * NSLAB + sl) * NH + h) * DIMC + c];
    s[(size_t)bh * DIMC + c] = acc;
}

// ---------------------------------------------------------------------------
// K3: x = Wv*s ; p = Wp*x + bp ; LN ; spike -> scale   (one block per b)
// ---------------------------------------------------------------------------
__global__ __launch_bounds__(256) void k_scale(const float* __restrict__ s,
                                               const float* __restrict__ Wkv,
                                               const float* __restrict__ Wp,
                                               const float* __restrict__ bp,
                                               const float* __restrict__ g,
                                               const float* __restrict__ beta,
                                               float* __restrict__ scale) {
    int b = blockIdx.x;
    int t = threadIdx.x;
    __shared__ float sL[NH][DIMC];
    __shared__ float xL[DIMC];
    __shared__ float red[8];
    __shared__ float mu_s, var_s;

    for (int h = 0; h < NH; ++h)
        sL[h][t] = s[((size_t)b * NH + h) * DIMC + t];
    __syncthreads();

    // x[i] = sum_c Wv[256+i][c] * s[i>>5][c]
    {
        const float* wr = Wkv + (size_t)(DIMC + t) * DIMC;
        const float* sr = sL[t >> 5];
        float acc = 0.f;
        for (int cc = 0; cc < DIMC; cc += 4) {
            float4 w = *(const float4*)(wr + cc);
            acc = fmaf(w.x, sr[cc], acc);
            acc = fmaf(w.y, sr[cc + 1], acc);
            acc = fmaf(w.z, sr[cc + 2], acc);
            acc = fmaf(w.w, sr[cc + 3], acc);
        }
        xL[t] = acc;
    }
    __syncthreads();

    float p;
    {
        const float* wr = Wp + (size_t)t * DIMC;
        float acc = 0.f;
        for (int i = 0; i < DIMC; i += 4) {
            float4 w = *(const float4*)(wr + i);
            acc = fmaf(w.x, xL[i], acc);
            acc = fmaf(w.y, xL[i + 1], acc);
            acc = fmaf(w.z, xL[i + 2], acc);
            acc = fmaf(w.w, xL[i + 3], acc);
        }
        p = acc + bp[t];
    }

    int lane = t & 63, wid = t >> 6;
    float r = p;
#pragma unroll
    for (int off = 32; off > 0; off >>= 1) r += __shfl_down(r, off);
    if (lane == 0) red[wid] = r;
    __syncthreads();
    if (t == 0) mu_s = (red[0] + red[1] + red[2] + red[3]) * (1.f / 256.f);
    __syncthreads();
    float mu = mu_s;
    float d = p - mu;
    float r2 = d * d;
#pragma unroll
    for (int off = 32; off > 0; off >>= 1) r2 += __shfl_down(r2, off);
    if (lane == 0) red[4 + wid] = r2;
    __syncthreads();
    if (t == 0) var_s = (red[4] + red[5] + red[6] + red[7]) * (1.f / 256.f);
    __syncthreads();

    float ln = d * (1.0f / sqrtf(var_s + LN_EPS)) * g[t] + beta[t];
    scale[b * DIMC + t] = rintf(fminf(fmaxf(ln, 0.f), 4.f)) * 0.25f;
}

// ---------------------------------------------------------------------------
// K4: out = fm * scale[b][c]
// ---------------------------------------------------------------------------
__global__ __launch_bounds__(256) void k_out(const float* __restrict__ fm,
                                             const float* __restrict__ scale,
                                             float* __restrict__ out) {
    const size_t total4 = (size_t)BATCH * DIMC * NPIX / 4;
    size_t stride = (size_t)gridDim.x * blockDim.x;
    size_t gid = (size_t)blockIdx.x * blockDim.x + threadIdx.x;
    for (size_t i = gid; i < total4; i += stride) {
        float4 v = *(const float4*)(fm + i * 4);
        float sval = scale[i >> 12];
        float4 o;
        o.x = v.x * sval; o.y = v.y * sval; o.z = v.z * sval; o.w = v.w * sval;
        *(float4*)(out + i * 4) = o;
    }
}

// ---------------------------------------------------------------------------
extern "C" void kernel_launch(void* const* d_in, const int* in_sizes, int n_in,
                              void* d_out, int out_size, void* d_ws, size_t ws_size,
                              hipStream_t stream) {
    (void)in_sizes; (void)n_in; (void)out_size; (void)ws_size;
    const float* fm    = (const float*)d_in[0];
    const float* audio = (const float*)d_in[1];
    const float* Wq    = (const float*)d_in[2];
    const float* Wkv   = (const float*)d_in[3];
    const float* Wp    = (const float*)d_in[4];
    const float* bp    = (const float*)d_in[5];
    const float* g     = (const float*)d_in[6];
    const float* beta  = (const float*)d_in[7];
    float* out = (float*)d_out;

    char* ws = (char*)d_ws;
    float* qk     = (float*)(ws);                               // 128 KB
    float* s_part = (float*)(ws + (size_t)131072);              // 4 MB (16*32*8*256*4)
    float* s      = (float*)(ws + (size_t)131072 + 4194304);    // 128 KB
    float* scale  = (float*)(ws + (size_t)131072 + 4194304 + 131072); // 16 KB

    hipLaunchKernelGGL(k_qk,    dim3(BATCH),       dim3(256), 0, stream, audio, Wq, Wkv, qk);
    hipLaunchKernelGGL(k_fused, dim3(BATCH * BPB), dim3(256), 0, stream, fm, qk, s_part);
    hipLaunchKernelGGL(k_red,   dim3(BATCH * NH),  dim3(256), 0, stream, s_part, s);
    hipLaunchKernelGGL(k_scale, dim3(BATCH),       dim3(256), 0, stream, s, Wkv, Wp, bp, g, beta, scale);
    hipLaunchKernelGGL(k_out,   dim3(2048),        dim3(256), 0, stream, fm, scale, out);
}

// Round 5
// 336.865 us; speedup vs baseline: 1.1944x; 1.1944x over previous
//
#include <hip/hip_runtime.h>
#include <math.h>

#define DIMC 256
#define NH 8
#define NPIX 16384          // 128*128
#define BATCH 16
#define ATT_SCALE 0.17677669529663687f   // 1/sqrt(32)
#define LN_EPS 1e-5f
#define NBLK_S 4            // n-splits in k_s

// ---------------------------------------------------------------------------
// K0: qk[b][h][c] = SCALE * sum_d q[b][h*32+d] * Wkv[h*32+d][c]
// ---------------------------------------------------------------------------
__global__ __launch_bounds__(256) void k_qk(const float* __restrict__ audio,
                                            const float* __restrict__ Wq,
                                            const float* __restrict__ Wkv,
                                            float* __restrict__ qk) {
    int b = blockIdx.x;
    int t = threadIdx.x;
    __shared__ float aud[DIMC];
    __shared__ float qL[DIMC];
    aud[t] = audio[b * DIMC + t];
    __syncthreads();
    {
        const float* wr = Wq + (size_t)t * DIMC;
        float acc = 0.f;
        for (int c = 0; c < DIMC; c += 4) {
            float4 w = *(const float4*)(wr + c);
            acc = fmaf(w.x, aud[c], acc);
            acc = fmaf(w.y, aud[c + 1], acc);
            acc = fmaf(w.z, aud[c + 2], acc);
            acc = fmaf(w.w, aud[c + 3], acc);
        }
        qL[t] = acc;
    }
    __syncthreads();
    {
        int c = t;
        float acc = 0.f;
        for (int i = 0; i < DIMC; ++i) {
            acc = fmaf(qL[i], Wkv[(size_t)i * DIMC + c], acc);
            if ((i & 31) == 31) {
                qk[((size_t)b * NH + (i >> 5)) * DIMC + c] = ATT_SCALE * acc;
                acc = 0.f;
            }
        }
    }
}

// ---------------------------------------------------------------------------
// K1: attn pass (streaming, no fm LDS). 256 blocks x 256 thr (8 waves/CU).
// Thread owns 4 consecutive n; loops all 256 c with coalesced b128 loads
// (1 KB/wave-instr); qk broadcast from LDS. a = spike(attn) -> global.
// ---------------------------------------------------------------------------
__global__ __launch_bounds__(256) void k_attn(const float* __restrict__ fm,
                                              const float* __restrict__ qk,
                                              float* __restrict__ a) {
    int blk  = blockIdx.x;
    int b    = blk >> 4;        // 16 n-blocks per batch
    int nblk = blk & 15;
    int t    = threadIdx.x;

    __shared__ float qkL[DIMC * NH];   // [c][h], 8 KB
    for (int h = 0; h < NH; ++h)
        qkL[t * NH + h] = qk[((size_t)b * NH + h) * DIMC + t];
    __syncthreads();

    const int n0 = nblk * 1024 + t * 4;
    const float* fmb = fm + (size_t)b * DIMC * NPIX + n0;

    float att[NH][4];
#pragma unroll
    for (int h = 0; h < NH; ++h)
        att[h][0] = att[h][1] = att[h][2] = att[h][3] = 0.f;

#pragma unroll 8
    for (int c = 0; c < DIMC; ++c) {
        float4 v = *(const float4*)(fmb + (size_t)c * NPIX);
        float4 q0 = *(const float4*)(qkL + c * NH);
        float4 q1 = *(const float4*)(qkL + c * NH + 4);
        att[0][0] = fmaf(v.x, q0.x, att[0][0]);
        att[0][1] = fmaf(v.y, q0.x, att[0][1]);
        att[0][2] = fmaf(v.z, q0.x, att[0][2]);
        att[0][3] = fmaf(v.w, q0.x, att[0][3]);
        att[1][0] = fmaf(v.x, q0.y, att[1][0]);
        att[1][1] = fmaf(v.y, q0.y, att[1][1]);
        att[1][2] = fmaf(v.z, q0.y, att[1][2]);
        att[1][3] = fmaf(v.w, q0.y, att[1][3]);
        att[2][0] = fmaf(v.x, q0.z, att[2][0]);
        att[2][1] = fmaf(v.y, q0.z, att[2][1]);
        att[2][2] = fmaf(v.z, q0.z, att[2][2]);
        att[2][3] = fmaf(v.w, q0.z, att[2][3]);
        att[3][0] = fmaf(v.x, q0.w, att[3][0]);
        att[3][1] = fmaf(v.y, q0.w, att[3][1]);
        att[3][2] = fmaf(v.z, q0.w, att[3][2]);
        att[3][3] = fmaf(v.w, q0.w, att[3][3]);
        att[4][0] = fmaf(v.x, q1.x, att[4][0]);
        att[4][1] = fmaf(v.y, q1.x, att[4][1]);
        att[4][2] = fmaf(v.z, q1.x, att[4][2]);
        att[4][3] = fmaf(v.w, q1.x, att[4][3]);
        att[5][0] = fmaf(v.x, q1.y, att[5][0]);
        att[5][1] = fmaf(v.y, q1.y, att[5][1]);
        att[5][2] = fmaf(v.z, q1.y, att[5][2]);
        att[5][3] = fmaf(v.w, q1.y, att[5][3]);
        att[6][0] = fmaf(v.x, q1.z, att[6][0]);
        att[6][1] = fmaf(v.y, q1.z, att[6][1]);
        att[6][2] = fmaf(v.z, q1.z, att[6][2]);
        att[6][3] = fmaf(v.w, q1.z, att[6][3]);
        att[7][0] = fmaf(v.x, q1.w, att[7][0]);
        att[7][1] = fmaf(v.y, q1.w, att[7][1]);
        att[7][2] = fmaf(v.z, q1.w, att[7][2]);
        att[7][3] = fmaf(v.w, q1.w, att[7][3]);
    }

#pragma unroll
    for (int h = 0; h < NH; ++h) {
        float4 o;
        o.x = rintf(fminf(fmaxf(att[h][0], 0.f), 4.f)) * 0.25f;
        o.y = rintf(fminf(fmaxf(att[h][1], 0.f), 4.f)) * 0.25f;
        o.z = rintf(fminf(fmaxf(att[h][2], 0.f), 4.f)) * 0.25f;
        o.w = rintf(fminf(fmaxf(att[h][3], 0.f), 4.f)) * 0.25f;
        *(float4*)(a + ((size_t)b * NH + h) * NPIX + n0) = o;
    }
}

// ---------------------------------------------------------------------------
// K2: s partials. grid = b(16) x nblk(4) x cblk(16) = 1024 blocks (4/CU).
// Thread = (c_local 16, nq 16): owns one c, strides n by 64. fm reads are
// 4x 256B segments/wave-instr; a reads are wave-shared (L1/L2 hit).
// LDS only for the final 16-way nq tree.
// ---------------------------------------------------------------------------
__global__ __launch_bounds__(256) void k_s(const float* __restrict__ fm,
                                           const float* __restrict__ a,
                                           float* __restrict__ s_part) {
    int blk  = blockIdx.x;
    int b    = blk >> 6;
    int nblk = (blk >> 4) & 3;
    int cblk = blk & 15;
    int t    = threadIdx.x;
    int c_l  = t >> 4;
    int nq   = t & 15;
    int c    = cblk * 16 + c_l;

    const float* fr = fm + ((size_t)b * DIMC + c) * NPIX + nblk * 4096 + nq * 4;
    const float* ab = a + (size_t)b * NH * NPIX + nblk * 4096 + nq * 4;

    float acc[NH];
#pragma unroll
    for (int h = 0; h < NH; ++h) acc[h] = 0.f;

#pragma unroll 2
    for (int j = 0; j < 64; ++j) {
        float4 v = *(const float4*)(fr + j * 64);
#pragma unroll
        for (int h = 0; h < NH; ++h) {
            float4 av = *(const float4*)(ab + (size_t)h * NPIX + j * 64);
            acc[h] += fmaf(v.x, av.x, fmaf(v.y, av.y, fmaf(v.z, av.z, v.w * av.w)));
        }
    }

    __shared__ float red[256 * NH];    // 8 KB
#pragma unroll
    for (int h = 0; h < NH; ++h) red[t * NH + h] = acc[h];
    __syncthreads();

    if (t < 128) {
        int cl = t >> 3, h = t & 7;
        float sum = 0.f;
#pragma unroll
        for (int q = 0; q < 16; ++q)
            sum += red[(cl * 16 + q) * NH + h];
        s_part[(((size_t)b * NBLK_S + nblk) * NH + h) * DIMC + cblk * 16 + cl] = sum;
    }
}

// ---------------------------------------------------------------------------
// K3: s[b][h][c] = sum over 4 n-splits
// ---------------------------------------------------------------------------
__global__ __launch_bounds__(256) void k_red(const float* __restrict__ s_part,
                                             float* __restrict__ s) {
    int bh = blockIdx.x;
    int b = bh >> 3, h = bh & 7;
    int c = threadIdx.x;
    float acc = 0.f;
    for (int sl = 0; sl < NBLK_S; ++sl)
        acc += s_part[(((size_t)b * NBLK_S + sl) * NH + h) * DIMC + c];
    s[(size_t)bh * DIMC + c] = acc;
}

// ---------------------------------------------------------------------------
// K4: x = Wv*s ; p = Wp*x + bp ; LN ; spike -> scale
// ---------------------------------------------------------------------------
__global__ __launch_bounds__(256) void k_scale(const float* __restrict__ s,
                                               const float* __restrict__ Wkv,
                                               const float* __restrict__ Wp,
                                               const float* __restrict__ bp,
                                               const float* __restrict__ g,
                                               const float* __restrict__ beta,
                                               float* __restrict__ scale) {
    int b = blockIdx.x;
    int t = threadIdx.x;
    __shared__ float sL[NH][DIMC];
    __shared__ float xL[DIMC];
    __shared__ float red[8];
    __shared__ float mu_s, var_s;

    for (int h = 0; h < NH; ++h)
        sL[h][t] = s[((size_t)b * NH + h) * DIMC + t];
    __syncthreads();

    {
        const float* wr = Wkv + (size_t)(DIMC + t) * DIMC;
        const float* sr = sL[t >> 5];
        float acc = 0.f;
        for (int cc = 0; cc < DIMC; cc += 4) {
            float4 w = *(const float4*)(wr + cc);
            acc = fmaf(w.x, sr[cc], acc);
            acc = fmaf(w.y, sr[cc + 1], acc);
            acc = fmaf(w.z, sr[cc + 2], acc);
            acc = fmaf(w.w, sr[cc + 3], acc);
        }
        xL[t] = acc;
    }
    __syncthreads();

    float p;
    {
        const float* wr = Wp + (size_t)t * DIMC;
        float acc = 0.f;
        for (int i = 0; i < DIMC; i += 4) {
            float4 w = *(const float4*)(wr + i);
            acc = fmaf(w.x, xL[i], acc);
            acc = fmaf(w.y, xL[i + 1], acc);
            acc = fmaf(w.z, xL[i + 2], acc);
            acc = fmaf(w.w, xL[i + 3], acc);
        }
        p = acc + bp[t];
    }

    int lane = t & 63, wid = t >> 6;
    float r = p;
#pragma unroll
    for (int off = 32; off > 0; off >>= 1) r += __shfl_down(r, off);
    if (lane == 0) red[wid] = r;
    __syncthreads();
    if (t == 0) mu_s = (red[0] + red[1] + red[2] + red[3]) * (1.f / 256.f);
    __syncthreads();
    float mu = mu_s;
    float d = p - mu;
    float r2 = d * d;
#pragma unroll
    for (int off = 32; off > 0; off >>= 1) r2 += __shfl_down(r2, off);
    if (lane == 0) red[4 + wid] = r2;
    __syncthreads();
    if (t == 0) var_s = (red[4] + red[5] + red[6] + red[7]) * (1.f / 256.f);
    __syncthreads();

    float ln = d * (1.0f / sqrtf(var_s + LN_EPS)) * g[t] + beta[t];
    scale[b * DIMC + t] = rintf(fminf(fmaxf(ln, 0.f), 4.f)) * 0.25f;
}

// ---------------------------------------------------------------------------
// K5: out = fm * scale[b][c]
// ---------------------------------------------------------------------------
__global__ __launch_bounds__(256) void k_out(const float* __restrict__ fm,
                                             const float* __restrict__ scale,
                                             float* __restrict__ out) {
    const size_t total4 = (size_t)BATCH * DIMC * NPIX / 4;
    size_t stride = (size_t)gridDim.x * blockDim.x;
    size_t gid = (size_t)blockIdx.x * blockDim.x + threadIdx.x;
    for (size_t i = gid; i < total4; i += stride) {
        float4 v = *(const float4*)(fm + i * 4);
        float sval = scale[i >> 12];
        float4 o;
        o.x = v.x * sval; o.y = v.y * sval; o.z = v.z * sval; o.w = v.w * sval;
        *(float4*)(out + i * 4) = o;
    }
}

// ---------------------------------------------------------------------------
extern "C" void kernel_launch(void* const* d_in, const int* in_sizes, int n_in,
                              void* d_out, int out_size, void* d_ws, size_t ws_size,
                              hipStream_t stream) {
    (void)in_sizes; (void)n_in; (void)out_size; (void)ws_size;
    const float* fm    = (const float*)d_in[0];
    const float* audio = (const float*)d_in[1];
    const float* Wq    = (const float*)d_in[2];
    const float* Wkv   = (const float*)d_in[3];
    const float* Wp    = (const float*)d_in[4];
    const float* bp    = (const float*)d_in[5];
    const float* g     = (const float*)d_in[6];
    const float* beta  = (const float*)d_in[7];
    float* out = (float*)d_out;

    char* ws = (char*)d_ws;
    float* qk     = (float*)(ws);                                   // 128 KB
    float* a      = (float*)(ws + (size_t)131072);                  // 8 MB
    float* s_part = (float*)(ws + (size_t)131072 + 8388608);        // 2 MB
    float* s      = (float*)(ws + (size_t)131072 + 8388608 + 2097152);       // 128 KB
    float* scale  = (float*)(ws + (size_t)131072 + 8388608 + 2097152 + 131072); // 16 KB

    hipLaunchKernelGGL(k_qk,    dim3(BATCH),           dim3(256), 0, stream, audio, Wq, Wkv, qk);
    hipLaunchKernelGGL(k_attn,  dim3(BATCH * 16),      dim3(256), 0, stream, fm, qk, a);
    hipLaunchKernelGGL(k_s,     dim3(BATCH * 64),      dim3(256), 0, stream, fm, a, s_part);
    hipLaunchKernelGGL(k_red,   dim3(BATCH * NH),      dim3(256), 0, stream, s_part, s);
    hipLaunchKernelGGL(k_scale, dim3(BATCH),           dim3(256), 0, stream, s, Wkv, Wp, bp, g, beta, scale);
    hipLaunchKernelGGL(k_out,   dim3(2048),            dim3(256), 0, stream, fm, scale, out);
}

// Round 6
// 306.113 us; speedup vs baseline: 1.3144x; 1.1005x over previous
//
#include <hip/hip_runtime.h>
#include <math.h>

#define DIMC 256
#define NH 8
#define NPIX 16384          // 128*128
#define BATCH 16
#define ATT_SCALE 0.17677669529663687f   // 1/sqrt(32)
#define LN_EPS 1e-5f
#define NBLK_S 4            // n-splits in k_s

// ---------------------------------------------------------------------------
// K0: qkT[b][c][h] = SCALE * sum_d q[b][h*32+d] * Wkv[h*32+d][c]
//     with q[b][i] = sum_c audio[b][c] * Wq[i][c]
// Layout [c][h] so k_attn can read 8 h contiguously at uniform address.
// ---------------------------------------------------------------------------
__global__ __launch_bounds__(256) void k_qk(const float* __restrict__ audio,
                                            const float* __restrict__ Wq,
                                            const float* __restrict__ Wkv,
                                            float* __restrict__ qkT) {
    int b = blockIdx.x;
    int t = threadIdx.x;
    __shared__ float aud[DIMC];
    __shared__ float qL[DIMC];
    aud[t] = audio[b * DIMC + t];
    __syncthreads();
    {
        const float* wr = Wq + (size_t)t * DIMC;
        float acc = 0.f;
        for (int c = 0; c < DIMC; c += 4) {
            float4 w = *(const float4*)(wr + c);
            acc = fmaf(w.x, aud[c], acc);
            acc = fmaf(w.y, aud[c + 1], acc);
            acc = fmaf(w.z, aud[c + 2], acc);
            acc = fmaf(w.w, aud[c + 3], acc);
        }
        qL[t] = acc;
    }
    __syncthreads();
    {
        int c = t;
        float acc = 0.f;
        for (int i = 0; i < DIMC; ++i) {
            acc = fmaf(qL[i], Wkv[(size_t)i * DIMC + c], acc);
            if ((i & 31) == 31) {
                qkT[((size_t)b * DIMC + c) * NH + (i >> 5)] = ATT_SCALE * acc;
                acc = 0.f;
            }
        }
    }
}

// ---------------------------------------------------------------------------
// K1: attn pass (pure streaming). 512 blocks x 256 thr = 8 waves/CU (2/SIMD).
// Thread owns 2 consecutive n (float2, 512B/wave-instr); loops all 256 c.
// qkT reads are wave-uniform (b, c uniform) -> scalar s_load path, no LDS.
// a = spike(attn) -> global.
// ---------------------------------------------------------------------------
__global__ __launch_bounds__(256) void k_attn(const float* __restrict__ fm,
                                              const float* __restrict__ qkT,
                                              float* __restrict__ a) {
    int blk  = blockIdx.x;          // 512 = b*32 + nblk
    int b    = blk >> 5;
    int nblk = blk & 31;
    int t    = threadIdx.x;

    const int n0 = nblk * 512 + t * 2;
    const float* fmb = fm + (size_t)b * DIMC * NPIX + n0;
    const float* qb  = qkT + (size_t)b * DIMC * NH;

    float a0[NH], a1[NH];
#pragma unroll
    for (int h = 0; h < NH; ++h) { a0[h] = 0.f; a1[h] = 0.f; }

#pragma unroll 4
    for (int c = 0; c < DIMC; ++c) {
        float2 v  = *(const float2*)(fmb + (size_t)c * NPIX);
        float4 q0 = *(const float4*)(qb + c * NH);       // uniform -> s_load
        float4 q1 = *(const float4*)(qb + c * NH + 4);
        a0[0] = fmaf(v.x, q0.x, a0[0]); a1[0] = fmaf(v.y, q0.x, a1[0]);
        a0[1] = fmaf(v.x, q0.y, a0[1]); a1[1] = fmaf(v.y, q0.y, a1[1]);
        a0[2] = fmaf(v.x, q0.z, a0[2]); a1[2] = fmaf(v.y, q0.z, a1[2]);
        a0[3] = fmaf(v.x, q0.w, a0[3]); a1[3] = fmaf(v.y, q0.w, a1[3]);
        a0[4] = fmaf(v.x, q1.x, a0[4]); a1[4] = fmaf(v.y, q1.x, a1[4]);
        a0[5] = fmaf(v.x, q1.y, a0[5]); a1[5] = fmaf(v.y, q1.y, a1[5]);
        a0[6] = fmaf(v.x, q1.z, a0[6]); a1[6] = fmaf(v.y, q1.z, a1[6]);
        a0[7] = fmaf(v.x, q1.w, a0[7]); a1[7] = fmaf(v.y, q1.w, a1[7]);
    }

#pragma unroll
    for (int h = 0; h < NH; ++h) {
        float2 o;
        o.x = rintf(fminf(fmaxf(a0[h], 0.f), 4.f)) * 0.25f;
        o.y = rintf(fminf(fmaxf(a1[h], 0.f), 4.f)) * 0.25f;
        *(float2*)(a + ((size_t)b * NH + h) * NPIX + n0) = o;
    }
}

// ---------------------------------------------------------------------------
// K2: s partials. 1024 blocks (XCD-swizzled so the 16 blocks sharing one
// (b,nblk) a-slab land on one XCD's L2), 256 thr = 16 waves/CU.
// Thread = (c_local 16, nq 16): owns one c, strides n by 64.
// ---------------------------------------------------------------------------
__global__ __launch_bounds__(256) void k_s(const float* __restrict__ fm,
                                           const float* __restrict__ a,
                                           float* __restrict__ s_part) {
    int d    = blockIdx.x;
    int blk  = (d & 7) * 128 + (d >> 3);   // bijective: 1024 = 8 x 128
    int b    = blk >> 6;
    int nblk = (blk >> 4) & 3;
    int cblk = blk & 15;
    int t    = threadIdx.x;
    int c_l  = t >> 4;
    int nq   = t & 15;
    int c    = cblk * 16 + c_l;

    const float* fr = fm + ((size_t)b * DIMC + c) * NPIX + nblk * 4096 + nq * 4;
    const float* ab = a + (size_t)b * NH * NPIX + nblk * 4096 + nq * 4;

    float acc[NH];
#pragma unroll
    for (int h = 0; h < NH; ++h) acc[h] = 0.f;

#pragma unroll 2
    for (int j = 0; j < 64; ++j) {
        float4 v = *(const float4*)(fr + j * 64);
#pragma unroll
        for (int h = 0; h < NH; ++h) {
            float4 av = *(const float4*)(ab + (size_t)h * NPIX + j * 64);
            acc[h] += fmaf(v.x, av.x, fmaf(v.y, av.y, fmaf(v.z, av.z, v.w * av.w)));
        }
    }

    __shared__ float red[256 * NH];    // 8 KB
#pragma unroll
    for (int h = 0; h < NH; ++h) red[t * NH + h] = acc[h];
    __syncthreads();

    if (t < 128) {
        int cl = t >> 3, h = t & 7;
        float sum = 0.f;
#pragma unroll
        for (int q = 0; q < 16; ++q)
            sum += red[(cl * 16 + q) * NH + h];
        s_part[(((size_t)b * NBLK_S + nblk) * NH + h) * DIMC + cblk * 16 + cl] = sum;
    }
}

// ---------------------------------------------------------------------------
// K3: (merged reduce) s = sum s_part ; x = Wv*s ; p = Wp*x + bp ; LN ; spike
// one block per b, 256 threads
// ---------------------------------------------------------------------------
__global__ __launch_bounds__(256) void k_scale(const float* __restrict__ s_part,
                                               const float* __restrict__ Wkv,
                                               const float* __restrict__ Wp,
                                               const float* __restrict__ bp,
                                               const float* __restrict__ g,
                                               const float* __restrict__ beta,
                                               float* __restrict__ scale) {
    int b = blockIdx.x;
    int t = threadIdx.x;
    __shared__ float sL[NH][DIMC];
    __shared__ float xL[DIMC];
    __shared__ float red[8];
    __shared__ float mu_s, var_s;

    for (int h = 0; h < NH; ++h) {
        float acc = 0.f;
        for (int sl = 0; sl < NBLK_S; ++sl)
            acc += s_part[(((size_t)b * NBLK_S + sl) * NH + h) * DIMC + t];
        sL[h][t] = acc;
    }
    __syncthreads();

    {
        const float* wr = Wkv + (size_t)(DIMC + t) * DIMC;
        const float* sr = sL[t >> 5];
        float acc = 0.f;
        for (int cc = 0; cc < DIMC; cc += 4) {
            float4 w = *(const float4*)(wr + cc);
            acc = fmaf(w.x, sr[cc], acc);
            acc = fmaf(w.y, sr[cc + 1], acc);
            acc = fmaf(w.z, sr[cc + 2], acc);
            acc = fmaf(w.w, sr[cc + 3], acc);
        }
        xL[t] = acc;
    }
    __syncthreads();

    float p;
    {
        const float* wr = Wp + (size_t)t * DIMC;
        float acc = 0.f;
        for (int i = 0; i < DIMC; i += 4) {
            float4 w = *(const float4*)(wr + i);
            acc = fmaf(w.x, xL[i], acc);
            acc = fmaf(w.y, xL[i + 1], acc);
            acc = fmaf(w.z, xL[i + 2], acc);
            acc = fmaf(w.w, xL[i + 3], acc);
        }
        p = acc + bp[t];
    }

    int lane = t & 63, wid = t >> 6;
    float r = p;
#pragma unroll
    for (int off = 32; off > 0; off >>= 1) r += __shfl_down(r, off);
    if (lane == 0) red[wid] = r;
    __syncthreads();
    if (t == 0) mu_s = (red[0] + red[1] + red[2] + red[3]) * (1.f / 256.f);
    __syncthreads();
    float mu = mu_s;
    float dd = p - mu;
    float r2 = dd * dd;
#pragma unroll
    for (int off = 32; off > 0; off >>= 1) r2 += __shfl_down(r2, off);
    if (lane == 0) red[4 + wid] = r2;
    __syncthreads();
    if (t == 0) var_s = (red[4] + red[5] + red[6] + red[7]) * (1.f / 256.f);
    __syncthreads();

    float ln = dd * (1.0f / sqrtf(var_s + LN_EPS)) * g[t] + beta[t];
    scale[b * DIMC + t] = rintf(fminf(fmaxf(ln, 0.f), 4.f)) * 0.25f;
}

// ---------------------------------------------------------------------------
// K4: out = fm * scale[b][c]
// ---------------------------------------------------------------------------
__global__ __launch_bounds__(256) void k_out(const float* __restrict__ fm,
                                             const float* __restrict__ scale,
                                             float* __restrict__ out) {
    const size_t total4 = (size_t)BATCH * DIMC * NPIX / 4;
    size_t stride = (size_t)gridDim.x * blockDim.x;
    size_t gid = (size_t)blockIdx.x * blockDim.x + threadIdx.x;
    for (size_t i = gid; i < total4; i += stride) {
        float4 v = *(const float4*)(fm + i * 4);
        float sval = scale[i >> 12];
        float4 o;
        o.x = v.x * sval; o.y = v.y * sval; o.z = v.z * sval; o.w = v.w * sval;
        *(float4*)(out + i * 4) = o;
    }
}

// ---------------------------------------------------------------------------
extern "C" void kernel_launch(void* const* d_in, const int* in_sizes, int n_in,
                              void* d_out, int out_size, void* d_ws, size_t ws_size,
                              hipStream_t stream) {
    (void)in_sizes; (void)n_in; (void)out_size; (void)ws_size;
    const float* fm    = (const float*)d_in[0];
    const float* audio = (const float*)d_in[1];
    const float* Wq    = (const float*)d_in[2];
    const float* Wkv   = (const float*)d_in[3];
    const float* Wp    = (const float*)d_in[4];
    const float* bp    = (const float*)d_in[5];
    const float* g     = (const float*)d_in[6];
    const float* beta  = (const float*)d_in[7];
    float* out = (float*)d_out;

    char* ws = (char*)d_ws;
    float* qkT    = (float*)(ws);                                   // 128 KB
    float* a      = (float*)(ws + (size_t)131072);                  // 8 MB
    float* s_part = (float*)(ws + (size_t)131072 + 8388608);        // 512 KB
    float* scale  = (float*)(ws + (size_t)131072 + 8388608 + 524288); // 16 KB

    hipLaunchKernelGGL(k_qk,    dim3(BATCH),      dim3(256), 0, stream, audio, Wq, Wkv, qkT);
    hipLaunchKernelGGL(k_attn,  dim3(512),        dim3(256), 0, stream, fm, qkT, a);
    hipLaunchKernelGGL(k_s,     dim3(1024),       dim3(256), 0, stream, fm, a, s_part);
    hipLaunchKernelGGL(k_scale, dim3(BATCH),      dim3(256), 0, stream, s_part, Wkv, Wp, bp, g, beta, scale);
    hipLaunchKernelGGL(k_out,   dim3(2048),       dim3(256), 0, stream, fm, scale, out);
}